// Round 3
// baseline (6600.620 us; speedup 1.0000x reference)
//
#include <hip/hip_runtime.h>
#include <math.h>

#define B 64
#define TF 64
#define TE 32
#define E_DIM 40
#define H 100
#define H2 200
#define H3 300
#define SP 256
#define EV 20000
#define ROWS (B*TF)        // 4096
#define NCOLS 456          // 200 score cols + 256 Y cols
#define ELDS 67            // enc_lds row stride (word): 3k mod 32 distinct -> conflict-free

// ---------------- setup: W_T (att_W1 bottom + sp1_W enc part, transposed), v, c2 ----
__global__ __launch_bounds__(256) void k_setup(const float* att_W1, const float* sp1_W,
        const float* sp2_W, const float* sp2_b, float* W_T, float* v, float* c2) {
  int bid = blockIdx.x;
  if (bid < 182) {
    int idx = bid*256 + threadIdx.x;
    if (idx < NCOLS*H) {
      int c = idx / 100, k = idx - c*100;
      float val;
      if (c < H2) val = att_W1[(100+k)*H2 + c];
      else        val = sp1_W[(200+k)*SP + (c-200)];
      W_T[idx] = val;                       // W_T[c*100+k]
    }
  } else if (bid == 182) {
    int k = threadIdx.x;                    // 0..255
    float s = 0.f;
    for (int j = 0; j < SP; ++j) s += sp2_W[k*SP + j];
    v[k] = s * (1.f/256.f);
  } else {
    if (threadIdx.x == 0) {
      float s = 0.f;
      for (int j = 0; j < SP; ++j) s += sp2_b[j];
      *c2 = s * (1.f/256.f);
    }
  }
}

// ---------------- encoder xs = embed @ enc_W + enc_b[0] ----
__global__ __launch_bounds__(320) void k_embed(const int* enc_in, const float* femb,
        const float* enc_W, const float* enc_b, float* xs_all) {
  int row = blockIdx.x;
  int j = threadIdx.x;
  __shared__ __align__(16) float emb[E_DIM];
  int tok = enc_in[row];
  if (j < E_DIM) emb[j] = femb[tok*E_DIM + j];
  __syncthreads();
  if (j < H3) {
    float acc = enc_b[j];
    #pragma unroll
    for (int k = 0; k < E_DIM; ++k) acc += emb[k]*enc_W[k*H3 + j];
    xs_all[row*H3 + j] = acc;
  }
}

// ---------------- encoder GRU recurrence: one block per batch, U register-resident ----
__global__ __launch_bounds__(192) void k_enc(const float* __restrict__ enc_U,
        const float* __restrict__ enc_b, const float* __restrict__ xs_all,
        float* __restrict__ enc_T, float* __restrict__ h_state) {
  int b = blockIdx.x, t = threadIdx.x;
  __shared__ __align__(16) float hsh[104];
  __shared__ __align__(16) float hs[304];

  float2 Ur[100];
  float2 bias = {0.f, 0.f};
  if (t < 150) {
    const float* base = enc_U + 2*t;
    #pragma unroll
    for (int k = 0; k < 100; ++k) Ur[k] = *(const float2*)(base + k*H3);
    bias = *(const float2*)(enc_b + H3 + 2*t);
  }
  if (t < H) hsh[t] = 0.f;
  __syncthreads();

  #pragma unroll 1
  for (int step = 0; step < TF; ++step) {
    int row = b*TF + step;
    float xz = 0.f, xr = 0.f, xh = 0.f;
    if (t < H) {
      xz = xs_all[row*H3 + t];
      xr = xs_all[row*H3 + 100 + t];
      xh = xs_all[row*H3 + 200 + t];
    }
    if (t < 150) {
      float a0 = bias.x, a1 = bias.y;
      const float4* h4 = (const float4*)hsh;
      #pragma unroll
      for (int k4 = 0; k4 < 25; ++k4) {
        float4 hv = h4[k4];
        a0 += hv.x*Ur[k4*4+0].x + hv.y*Ur[k4*4+1].x + hv.z*Ur[k4*4+2].x + hv.w*Ur[k4*4+3].x;
        a1 += hv.x*Ur[k4*4+0].y + hv.y*Ur[k4*4+1].y + hv.z*Ur[k4*4+2].y + hv.w*Ur[k4*4+3].y;
      }
      hs[2*t]   = a0;
      hs[2*t+1] = a1;
    }
    __syncthreads();
    if (t < H) {
      float z = 1.f/(1.f+expf(-(xz + hs[t])));
      float r = 1.f/(1.f+expf(-(xr + hs[100+t])));
      float cand = tanhf(xh + r*hs[200+t]);
      float hn = z*hsh[t] + (1.f-z)*cand;
      hsh[t] = hn;
      enc_T[t*ROWS + row] = hn;
    }
    __syncthreads();
  }
  if (t < H) h_state[b*H + t] = hsh[t];
}

// ---------------- hW/q update helper (threads 64..463 compute 400 cols from src[100]) ----
__device__ __forceinline__ void hwq_update(int tid, const float* __restrict__ att_W1,
        const float* __restrict__ att_W2, const float* src, float* hWl, float* ql) {
  if (tid >= 64 && tid < 464) {
    int c = tid - 64;
    const float* Wm = (c < H2) ? att_W1 : att_W2;
    int col = (c < H2) ? c : c - H2;
    float a = 0.f;
    const float4* s4 = (const float4*)src;
    #pragma unroll
    for (int k4 = 0; k4 < 25; ++k4) {
      float4 sv = s4[k4]; int k = k4*4;
      a += sv.x*Wm[(k+0)*H2+col] + sv.y*Wm[(k+1)*H2+col]
         + sv.z*Wm[(k+2)*H2+col] + sv.w*Wm[(k+3)*H2+col];
    }
    if (c < H2) hWl[col] = a; else ql[col] = a;
  }
}

// ---------------- fused decoder: one block per batch, 512 threads, 32 steps internal ----
__global__ __launch_bounds__(512) void k_dec(const float* __restrict__ enc_T,
        const float* __restrict__ W_T, const float* __restrict__ h_state,
        const float* __restrict__ dec_W, const float* __restrict__ dec_U,
        const float* __restrict__ dec_b,
        const float* __restrict__ sp1_W, const float* __restrict__ sp1_b,
        const float* __restrict__ att_W1, const float* __restrict__ att_W2,
        const float* __restrict__ v, const float* __restrict__ c2p,
        float* __restrict__ dec_out) {
  int b = blockIdx.x, tid = threadIdx.x;
  int w = tid >> 6, lane = tid & 63;

  __shared__ __align__(16) float enc_lds[H*ELDS];   // [k][t] stride 67
  __shared__ __align__(16) float rd[104];
  __shared__ __align__(16) float h[104];
  __shared__ __align__(16) float hnew[104];
  __shared__ __align__(16) float xs[304];
  __shared__ __align__(16) float hs[304];
  __shared__ __align__(16) float hWl[200];
  __shared__ __align__(16) float ql[200];
  __shared__ __align__(16) float ccp[2][256];
  __shared__ float alpha[64];
  __shared__ float gg[64];
  __shared__ float red[8][64];

  // ---- prologue: load enc into LDS + per-lane regs, h, initial hW/q ----
  for (int idx = tid; idx < H*64; idx += 512) {
    int k = idx >> 6, t = idx & 63;
    enc_lds[k*ELDS + t] = enc_T[k*ROWS + b*64 + t];
  }
  float e[H];
  #pragma unroll
  for (int k = 0; k < H; ++k) e[k] = enc_T[k*ROWS + b*64 + lane];
  if (tid < H) { float hv = h_state[b*H + tid]; h[tid] = hv; hnew[tid] = hv; }
  __syncthreads();
  hwq_update(tid, att_W1, att_W2, hnew, hWl, ql);
  float c2v = *c2p;
  __syncthreads();

  #pragma unroll 1
  for (int s = 0; s < TE; ++s) {
    // ---- P1: score cols (c = w + 8i, i<25): acc = e . W_T[c], sp += tanh(hW+acc)*q ----
    {
      float sp = 0.f;
      #pragma unroll 1
      for (int i = 0; i < 25; ++i) {
        int cu = __builtin_amdgcn_readfirstlane(w + i*8);
        const float* wr = W_T + cu*100;
        float acc = 0.f;
        #pragma unroll
        for (int k = 0; k < H; ++k) acc += e[k]*wr[k];
        sp += tanhf(hWl[cu] + acc) * ql[cu];
      }
      red[w][lane] = sp;
    }
    __syncthreads();
    // ---- P2: softmax over t (wave 0) ----
    if (w == 0) {
      float sc = red[0][lane] + red[1][lane] + red[2][lane] + red[3][lane]
               + red[4][lane] + red[5][lane] + red[6][lane] + red[7][lane];
      float m = sc;
      #pragma unroll
      for (int mask = 32; mask >= 1; mask >>= 1) m = fmaxf(m, __shfl_xor(m, mask));
      float ex = expf(sc - m);
      float ssum = ex;
      #pragma unroll
      for (int mask = 32; mask >= 1; mask >>= 1) ssum += __shfl_xor(ssum, mask);
      alpha[lane] = ex / ssum;
    }
    __syncthreads();
    // ---- P3: rd[k] = sum_t alpha[t]*enc[k][t]  (threads 0..99) ----
    if (tid < H) {
      float r = 0.f;
      #pragma unroll
      for (int t = 0; t < 64; ++t) r += alpha[t]*enc_lds[tid*ELDS + t];
      rd[tid] = r;
    }
    __syncthreads();
    // ---- P4: GRU matvecs xs = rd@dec_W + b0 ; hs = h@dec_U + b1 ----
    for (int jj = tid; jj < 600; jj += 512) {
      if (jj < H3) {
        float ax = dec_b[jj];
        const float4* r4 = (const float4*)rd;
        #pragma unroll
        for (int k4 = 0; k4 < 25; ++k4) {
          float4 rv = r4[k4]; int k = k4*4;
          ax += rv.x*dec_W[(k+0)*H3+jj] + rv.y*dec_W[(k+1)*H3+jj]
              + rv.z*dec_W[(k+2)*H3+jj] + rv.w*dec_W[(k+3)*H3+jj];
        }
        xs[jj] = ax;
      } else {
        int j = jj - H3;
        float ah = dec_b[H3 + j];
        const float4* h4 = (const float4*)h;
        #pragma unroll
        for (int k4 = 0; k4 < 25; ++k4) {
          float4 hv = h4[k4]; int k = k4*4;
          ah += hv.x*dec_U[(k+0)*H3+j] + hv.y*dec_U[(k+1)*H3+j]
              + hv.z*dec_U[(k+2)*H3+j] + hv.w*dec_U[(k+3)*H3+j];
        }
        hs[j] = ah;
      }
    }
    __syncthreads();
    // ---- P5: GRU gates -> hnew, h, dec_out ----
    if (tid < H) {
      float z = 1.f/(1.f+expf(-(xs[tid] + hs[tid])));
      float r = 1.f/(1.f+expf(-(xs[100+tid] + hs[100+tid])));
      float cand = tanhf(xs[200+tid] + r*hs[200+tid]);
      float hn = z*h[tid] + (1.f-z)*cand;
      hnew[tid] = hn; h[tid] = hn;
      dec_out[(b*TE + s)*H + tid] = hn;
    }
    __syncthreads();
    if (s == TE-1) break;                   // gate/enc-update/hW-q dead on last step
    // ---- P6: cc partials (k-split over 512 threads) ----
    {
      int kh = tid >> 8, jj = tid & 255;
      const float* inv = kh ? rd : hnew;
      const float* wb = sp1_W + kh*100*SP;
      float a = kh ? 0.f : sp1_b[jj];
      const float4* i4 = (const float4*)inv;
      #pragma unroll
      for (int k4 = 0; k4 < 25; ++k4) {
        float4 iv = i4[k4]; int k = k4*4;
        a += iv.x*wb[(k+0)*SP+jj] + iv.y*wb[(k+1)*SP+jj]
           + iv.z*wb[(k+2)*SP+jj] + iv.w*wb[(k+3)*SP+jj];
      }
      ccp[kh][jj] = a;
    }
    __syncthreads();
    // ---- P7: Y cols (c = 200 + w + 8i) computed and consumed immediately by gate-dot ----
    {
      float gp = 0.f;
      #pragma unroll 1
      for (int i = 0; i < 32; ++i) {
        int cu = __builtin_amdgcn_readfirstlane(w + i*8);   // Y col index 0..255
        const float* wr = W_T + (H2 + cu)*100;
        float acc = 0.f;
        #pragma unroll
        for (int k = 0; k < H; ++k) acc += e[k]*wr[k];
        float y = ccp[0][cu] + ccp[1][cu] + acc;
        gp += fmaxf(y, 0.f) * v[cu];
      }
      red[w][lane] = gp;
    }
    __syncthreads();
    if (w == 0) {
      float gd = red[0][lane] + red[1][lane] + red[2][lane] + red[3][lane]
               + red[4][lane] + red[5][lane] + red[6][lane] + red[7][lane] + c2v;
      gg[lane] = 1.f/(1.f+expf(-gd));
    }
    __syncthreads();
    // ---- P8: enc update (regs + LDS) and next-step hW/q ----
    {
      float g = gg[lane];
      #pragma unroll
      for (int k = 0; k < H; ++k) e[k] = g*e[k] + (1.f-g)*rd[k];
      if (w == 0) {
        #pragma unroll
        for (int k = 0; k < H; ++k) enc_lds[k*ELDS + lane] = e[k];
      }
      hwq_update(tid, att_W1, att_W2, hnew, hWl, ql);
    }
    __syncthreads();
  }
}

// ---------------- ff1: hid = relu(dec_out @ ff1_W + b) ----
__global__ __launch_bounds__(128) void k_ff1(const float* dec_out, const float* ff1_W,
        const float* ff1_b, float* hid) {
  int row = blockIdx.x, j = threadIdx.x;
  __shared__ __align__(16) float a[104];
  if (j < H) a[j] = dec_out[row*H + j];
  __syncthreads();
  if (j < H) {
    float acc = ff1_b[j];
    const float4* a4 = (const float4*)a;
    #pragma unroll
    for (int k4 = 0; k4 < 25; ++k4) {
      float4 av = a4[k4]; int k = k4*4;
      acc += av.x*ff1_W[(k+0)*H+j] + av.y*ff1_W[(k+1)*H+j]
           + av.z*ff1_W[(k+2)*H+j] + av.w*ff1_W[(k+3)*H+j];
    }
    hid[row*H + j] = fmaxf(acc, 0.f);
  }
}

// ---------------- logits GEMM: [2048,100] x [100,20000], reg-prefetch double-step ----
#define KC 20
__global__ __launch_bounds__(256) void k_logits(const float* __restrict__ hid,
        const float* __restrict__ ff2_W, const float* __restrict__ ff2_b,
        float* __restrict__ out) {
  int bx = blockIdx.x, by = blockIdx.y;
  int tid = threadIdx.x;
  int tx = tid & 15, ty = tid >> 4;
  __shared__ __align__(16) float At[100*128];     // 51200 B
  __shared__ __align__(16) float Wt[KC*128];      // 10240 B
  int r0 = by*128;
  int c0 = bx*128;
  // stage A (coalesced float4 row reads, transposed store)
  for (int i = tid; i < 128*25; i += 256) {
    int r = i / 25, kq = i % 25;
    float4 hv = *(const float4*)(hid + (size_t)(r0+r)*H + kq*4);
    At[(kq*4+0)*128 + r] = hv.x;
    At[(kq*4+1)*128 + r] = hv.y;
    At[(kq*4+2)*128 + r] = hv.z;
    At[(kq*4+3)*128 + r] = hv.w;
  }
  // prefetch kc=0 W chunk into regs
  float wreg[10];
  #pragma unroll
  for (int j = 0; j < 10; ++j) {
    int i = tid + j*256;
    int kk = i >> 7, c = i & 127;
    int gc = c0 + c;
    wreg[j] = (gc < EV) ? ff2_W[(size_t)kk*EV + gc] : 0.f;
  }
  __syncthreads();
  #pragma unroll
  for (int j = 0; j < 10; ++j) {
    int i = tid + j*256;
    Wt[(i >> 7)*128 + (i & 127)] = wreg[j];
  }
  __syncthreads();

  float acc[8][8];
  #pragma unroll
  for (int i = 0; i < 8; ++i)
    #pragma unroll
    for (int j = 0; j < 8; ++j) acc[i][j] = 0.f;

  #pragma unroll 1
  for (int kc = 0; kc < 100; kc += KC) {
    // prefetch next chunk while computing this one
    if (kc + KC < 100) {
      #pragma unroll
      for (int j = 0; j < 10; ++j) {
        int i = tid + j*256;
        int kk = i >> 7, c = i & 127;
        int gc = c0 + c;
        wreg[j] = (gc < EV) ? ff2_W[(size_t)(kc+KC+kk)*EV + gc] : 0.f;
      }
    }
    #pragma unroll
    for (int kk = 0; kk < KC; ++kk) {
      const float* Ar = At + (kc+kk)*128;
      const float* Wr = Wt + kk*128;
      float4 a0 = *(const float4*)(Ar + ty*4);
      float4 a1 = *(const float4*)(Ar + 64 + ty*4);
      float4 w0 = *(const float4*)(Wr + tx*4);
      float4 w1 = *(const float4*)(Wr + 64 + tx*4);
      float av[8] = {a0.x,a0.y,a0.z,a0.w,a1.x,a1.y,a1.z,a1.w};
      float wv[8] = {w0.x,w0.y,w0.z,w0.w,w1.x,w1.y,w1.z,w1.w};
      #pragma unroll
      for (int i = 0; i < 8; ++i)
        #pragma unroll
        for (int j = 0; j < 8; ++j) acc[i][j] += av[i]*wv[j];
    }
    if (kc + KC < 100) {
      __syncthreads();
      #pragma unroll
      for (int j = 0; j < 10; ++j) {
        int i = tid + j*256;
        Wt[(i >> 7)*128 + (i & 127)] = wreg[j];
      }
      __syncthreads();
    }
  }
  #pragma unroll
  for (int i = 0; i < 8; ++i) {
    int r = r0 + ty*4 + (i < 4 ? i : 60 + i);
    float* orow = out + (size_t)r*EV;
    int ca = c0 + tx*4;
    if (ca < EV) {
      float4 bb = *(const float4*)(ff2_b + ca);
      float4 val = {acc[i][0]+bb.x, acc[i][1]+bb.y, acc[i][2]+bb.z, acc[i][3]+bb.w};
      *(float4*)(orow + ca) = val;
    }
    int cb = c0 + 64 + tx*4;
    if (cb < EV) {
      float4 bb = *(const float4*)(ff2_b + cb);
      float4 val = {acc[i][4]+bb.x, acc[i][5]+bb.y, acc[i][6]+bb.z, acc[i][7]+bb.w};
      *(float4*)(orow + cb) = val;
    }
  }
}

// ---------------- in-place row softmax on d_out ----
__global__ __launch_bounds__(256) void k_softmax(float* out) {
  int row = blockIdx.x, tid = threadIdx.x;
  float* p = out + (size_t)row*EV;
  float m = -1e30f, ssum = 0.f;
  for (int j = tid; j < EV; j += 256) {
    float x = p[j];
    if (x > m) { ssum = ssum*expf(m - x) + 1.f; m = x; }
    else ssum += expf(x - m);
  }
  __shared__ float sm[256], ss[256];
  sm[tid] = m; ss[tid] = ssum;
  __syncthreads();
  for (int st = 128; st >= 1; st >>= 1) {
    if (tid < st) {
      float m2 = sm[tid+st], s2 = ss[tid+st];
      float M = fmaxf(sm[tid], m2);
      ss[tid] = ss[tid]*expf(sm[tid]-M) + s2*expf(m2-M);
      sm[tid] = M;
    }
    __syncthreads();
  }
  float M = sm[0];
  float inv = 1.f/ss[0];
  for (int j = tid; j < EV; j += 256) {
    p[j] = expf(p[j] - M) * inv;
  }
}

extern "C" void kernel_launch(void* const* d_in, const int* in_sizes, int n_in,
                              void* d_out, int out_size, void* d_ws, size_t ws_size,
                              hipStream_t stream) {
  (void)in_sizes; (void)n_in; (void)out_size;
  const int*   enc_in  = (const int*)d_in[0];
  const float* femb    = (const float*)d_in[2];
  const float* enc_W   = (const float*)d_in[4];
  const float* enc_U   = (const float*)d_in[5];
  const float* enc_b   = (const float*)d_in[6];
  const float* dec_W   = (const float*)d_in[7];
  const float* dec_U   = (const float*)d_in[8];
  const float* dec_b   = (const float*)d_in[9];
  const float* att_W1  = (const float*)d_in[10];
  const float* att_W2  = (const float*)d_in[11];
  const float* sp1_W   = (const float*)d_in[12];
  const float* sp1_b   = (const float*)d_in[13];
  const float* sp2_W   = (const float*)d_in[14];
  const float* sp2_b   = (const float*)d_in[15];
  const float* ff1_W   = (const float*)d_in[16];
  const float* ff1_b   = (const float*)d_in[17];
  const float* ff2_W   = (const float*)d_in[18];
  const float* ff2_b   = (const float*)d_in[19];
  float* out = (float*)d_out;
  float* ws  = (float*)d_ws;

  float* enc_T  = ws + 0;          // 100*4096  = 409600
  float* W_T    = ws + 409600;     // 456*100   = 45600
  float* h_st   = ws + 1562144;    // 64*100    = 6400
  float* dec_o  = ws + 1568544;    // 2048*100  = 204800
  float* hid    = ws + 1773344;    // 2048*100  = 204800
  float* xs_all = ws + 1978144;    // 4096*300  = 1228800
  float* vbuf   = ws + 3206944;    // 256
  float* c2buf  = ws + 3207200;    // 1
  if (ws_size < (size_t)3207232*4) return;   // need ~12.8 MB

  k_setup<<<184, 256, 0, stream>>>(att_W1, sp1_W, sp2_W, sp2_b, W_T, vbuf, c2buf);
  k_embed<<<4096, 320, 0, stream>>>(enc_in, femb, enc_W, enc_b, xs_all);
  k_enc<<<64, 192, 0, stream>>>(enc_U, enc_b, xs_all, enc_T, h_st);
  k_dec<<<64, 512, 0, stream>>>(enc_T, W_T, h_st, dec_W, dec_U, dec_b, sp1_W, sp1_b,
                                att_W1, att_W2, vbuf, c2buf, dec_o);
  k_ff1<<<2048, 128, 0, stream>>>(dec_o, ff1_W, ff1_b, hid);
  k_logits<<<dim3(157, 16), 256, 0, stream>>>(hid, ff2_W, ff2_b, out);
  k_softmax<<<2048, 256, 0, stream>>>(out);
}